// Round 10
// baseline (381.388 us; speedup 1.0000x reference)
//
#include <hip/hip_runtime.h>
#include <hip/hip_bf16.h>
#include <math.h>

// ---------------------------------------------------------------------------
// Gated causal attention block, bf16 MFMA pipeline. B=2,N=2048,DIM=2048,H=16,DH=128.
// R10: R9 regressed (single-buffer serialization + 35% more staged KV) ->
//     reverted to R8's dual-q counted-vmcnt attn, then scaled it to 512
//     threads / 8 waves / 128-row q-super-tiles paired (p,15-p): staged KV
//     volume 402MB -> 205MB (the ~52us modeled floor halves). Per-wave math
//     identical to R8. Also fused cvt_bf16+gates (saves one 67MB x pass).
//     GEMMs unchanged from R8.
// ---------------------------------------------------------------------------

typedef __attribute__((ext_vector_type(8))) __bf16 bf16x8;
typedef __attribute__((ext_vector_type(4))) __bf16 bf16x4;
typedef __attribute__((ext_vector_type(4))) float f32x4;

#define MFMA_BF16(a, b, c) __builtin_amdgcn_mfma_f32_16x16x32_bf16((a), (b), (c), 0, 0, 0)

#define NB 2
#define NSEQ 2048
#define NDIM 2048
#define NH 16
#define NDH 128
#define SCALE_Q 0.08838834764831845f /* 128^-0.5 */

#define AS1 __attribute__((address_space(1)))
#define AS3 __attribute__((address_space(3)))
static __device__ __forceinline__ void gload_lds16(const void* g, void* l) {
  __builtin_amdgcn_global_load_lds((AS1 const void*)g, (AS3 void*)l, 16, 0, 0);
}

static __device__ __forceinline__ unsigned pack2_bf16(float a, float b) {
  unsigned short ua = __builtin_bit_cast(unsigned short, (__bf16)a);
  unsigned short ub = __builtin_bit_cast(unsigned short, (__bf16)b);
  return (unsigned)ua | ((unsigned)ub << 16);
}

// ---------------------------------------------------------------------------
// Fused x->bf16 conversion + gates. One block per row (b*N+n): reads the 8KB
// row once, writes 4KB bf16, accumulates the 16 gate dots (w_gates L2-hot).
__global__ __launch_bounds__(256) void cvt_gates_kernel(const float* __restrict__ x,
                                                        const float* __restrict__ wg,
                                                        __bf16* __restrict__ x_bf,
                                                        float* __restrict__ gates) {
  __shared__ float red[64];
  int row = blockIdx.x;
  int tid = threadIdx.x;
  const float* xr = x + (size_t)row * NDIM;
  int k0 = tid * 8;
  float4 v0 = *reinterpret_cast<const float4*>(xr + k0);
  float4 v1 = *reinterpret_cast<const float4*>(xr + k0 + 4);
  float vv[8] = {v0.x, v0.y, v0.z, v0.w, v1.x, v1.y, v1.z, v1.w};
  union { bf16x8 v; } o;
#pragma unroll
  for (int j = 0; j < 8; ++j) o.v[j] = (__bf16)vv[j];
  *reinterpret_cast<bf16x8*>(x_bf + (size_t)row * NDIM + k0) = o.v;

  float acc[16];
#pragma unroll
  for (int h = 0; h < 16; ++h) acc[h] = 0.f;
#pragma unroll
  for (int j = 0; j < 8; ++j) {
    const float* wr = wg + (size_t)(k0 + j) * NH;
#pragma unroll
    for (int h = 0; h < 16; ++h) acc[h] += vv[j] * wr[h];
  }
  int w = tid >> 6, lane = tid & 63;
#pragma unroll
  for (int h = 0; h < 16; ++h) {
    float v = acc[h];
#pragma unroll
    for (int off = 32; off; off >>= 1) v += __shfl_down(v, off);
    if (lane == 0) red[w * 16 + h] = v;
  }
  __syncthreads();
  if (tid < 16) {
    float s = red[tid] + red[16 + tid] + red[32 + tid] + red[48 + tid];
    int b = row >> 11, n = row & 2047;
    gates[((size_t)(b * NH + tid)) * NSEQ + n] = 1.f / (1.f + expf(-s));
  }
}

// in: f32 [K][C] row-major -> out: bf16 [C][K] row-major
__global__ __launch_bounds__(256) void transpose_cvt_kernel(const float* __restrict__ in,
                                                            __bf16* __restrict__ out,
                                                            int K, int C) {
  __shared__ float tile[32][33];
  int c0 = blockIdx.x * 32, k0 = blockIdx.y * 32;
  int t = threadIdx.x;
  int lc = t & 31, lr = t >> 5;
#pragma unroll
  for (int rr = 0; rr < 4; ++rr)
    tile[lr + rr * 8][lc] = in[(size_t)(k0 + lr + rr * 8) * C + c0 + lc];
  __syncthreads();
#pragma unroll
  for (int rr = 0; rr < 4; ++rr)
    out[(size_t)(c0 + lr + rr * 8) * K + k0 + lc] = (__bf16)tile[lc][lr + rr * 8];
}

// ---------------------------------------------------------------------------
// qkv core (unchanged R8): BM=256, BN=384, BK=32, 8 waves, LDS ring-of-3.
struct SmemQ {
  __bf16 T[3][640][32];  // 120 KiB
};

static __device__ __forceinline__ const bf16x8* fragq(const __bf16* base, int row, int g) {
  return (const bf16x8*)(base + row * 32 + (g ^ ((row >> 1) & 3)) * 8);
}

__global__ __launch_bounds__(512, 2) void gemm_qkv256b(const __bf16* __restrict__ A,
                                                       const __bf16* __restrict__ Bt,
                                                       __bf16* __restrict__ qb,
                                                       __bf16* __restrict__ kb,
                                                       __bf16* __restrict__ vtb) {
  __shared__ __align__(1024) SmemQ S;
  int sblk = blockIdx.x;
  int x = sblk & 7, i = sblk >> 3;
  int m0 = (i >> 1) * 256;
  int n0 = (2 * x + (i & 1)) * 384;
  const __bf16* Ab = A + (size_t)m0 * 2048;
  const __bf16* Bb = Bt + (size_t)n0 * 2048;

  int tid = threadIdx.x;
  int w = tid >> 6, lane = tid & 63;
  int ln15 = lane & 15, g = lane >> 4;
  int wr = w >> 2, wc = w & 3;
  int lr4 = lane >> 2, l3 = lane & 3;

  auto stage = [&](int kt, int rb) {
#pragma unroll
    for (int j = 0; j < 5; ++j) {
      int k = w + 8 * j;
      int row = k * 16 + lr4;
      int sg = l3 ^ ((row >> 1) & 3);
      const __bf16* src = (k < 16)
          ? Ab + (size_t)row * 2048 + kt * 32 + sg * 8
          : Bb + (size_t)(row - 256) * 2048 + kt * 32 + sg * 8;
      gload_lds16(src, &S.T[rb][k * 16][0]);
    }
  };

  f32x4 acc[8][6];
#pragma unroll
  for (int a = 0; a < 8; ++a)
#pragma unroll
    for (int nf = 0; nf < 6; ++nf) acc[a][nf] = (f32x4){0.f, 0.f, 0.f, 0.f};

  stage(0, 0);
  stage(1, 1);
  for (int t = 0; t < 64; ++t) {
    int rb = t % 3;
    asm volatile("s_waitcnt vmcnt(5)" ::: "memory");
    __builtin_amdgcn_s_barrier();
    asm volatile("" ::: "memory");
    int ts = (t < 62) ? t + 2 : 63;
    stage(ts, (t + 2) % 3);
    const __bf16* Sb = &S.T[rb][0][0];
    bf16x8 bfr[6];
#pragma unroll
    for (int nf = 0; nf < 6; ++nf) {
      int row = 256 + wc * 96 + nf * 16 + ln15;
      bfr[nf] = *fragq(Sb, row, g);
    }
#pragma unroll
    for (int mh = 0; mh < 2; ++mh) {
      bf16x8 af[4];
#pragma unroll
      for (int a = 0; a < 4; ++a) {
        int row = wr * 128 + (mh * 4 + a) * 16 + ln15;
        af[a] = *fragq(Sb, row, g);
      }
      __builtin_amdgcn_s_setprio(1);
#pragma unroll
      for (int a = 0; a < 4; ++a)
#pragma unroll
        for (int nf = 0; nf < 6; ++nf)
          acc[mh * 4 + a][nf] = MFMA_BF16(af[a], bfr[nf], acc[mh * 4 + a][nf]);
      __builtin_amdgcn_s_setprio(0);
    }
  }
  asm volatile("s_waitcnt vmcnt(0)" ::: "memory");

#pragma unroll
  for (int nf = 0; nf < 6; ++nf) {
    int ng = n0 + wc * 96 + nf * 16 + ln15;
    int qkv = ng >> 11;
    int h = (ng >> 7) & 15;
    int d = ng & 127;
#pragma unroll
    for (int mf = 0; mf < 8; ++mf)
#pragma unroll
      for (int rr = 0; rr < 4; ++rr) {
        int m = m0 + wr * 128 + mf * 16 + g * 4 + rr;
        int b = m >> 11, n = m & 2047;
        int bh = b * NH + h;
        float v = acc[mf][nf][rr];
        if (qkv == 0)
          qb[((size_t)bh * NSEQ + n) * NDH + d] = (__bf16)(v * SCALE_Q);
        else if (qkv == 1)
          kb[((size_t)bh * NSEQ + n) * NDH + d] = (__bf16)v;
        else
          vtb[((size_t)bh * NDH + d) * NSEQ + n] = (__bf16)v;
      }
  }
}

// ---------------------------------------------------------------------------
// gemm_out core (unchanged): BM=128 x BN=256, BK=64, 8 waves.
template <int BN> struct SmemG {
  __bf16 A[2][2][128][32];
  __bf16 B[2][2][BN][32];
};

template <int BN>
static __device__ __forceinline__ void stage_half(const __bf16* __restrict__ Ab,
                                                  const __bf16* __restrict__ Bb,
                                                  SmemG<BN>* S, int buf, int ks,
                                                  int kt, int w, int lane) {
  constexpr int LB = BN / 128;
  {
    int gid = w * 64 + lane;
    int row = gid >> 2, gc = gid & 3;
    int sg = gc ^ ((row >> 1) & 3);
    gload_lds16(Ab + (size_t)row * 2048 + kt * 64 + ks * 32 + sg * 8,
                &S->A[buf][ks][0][0] + (size_t)(w * 64) * 8);
  }
#pragma unroll
  for (int j = 0; j < LB; ++j) {
    int gid = j * 512 + w * 64 + lane;
    int row = gid >> 2, gc = gid & 3;
    int sg = gc ^ ((row >> 1) & 3);
    gload_lds16(Bb + (size_t)row * 2048 + kt * 64 + ks * 32 + sg * 8,
                &S->B[buf][ks][0][0] + (size_t)(j * 512 + w * 64) * 8);
  }
}

static __device__ __forceinline__ const bf16x8* fragp(const __bf16* base, int row, int g) {
  return (const bf16x8*)(base + row * 32 + (g ^ ((row >> 1) & 3)) * 8);
}

template <int BN>
static __device__ __forceinline__ void gemm128_core(const __bf16* __restrict__ Abase,
                                                    const __bf16* __restrict__ Bbase,
                                                    SmemG<BN>* S,
                                                    f32x4 (*acc)[BN / 64]) {
  constexpr int NF = BN / 64;
  constexpr int LB = BN / 128;
  int tid = threadIdx.x;
  int w = tid >> 6, lane = tid & 63;
  int ln15 = lane & 15, g = lane >> 4;
  int wr = w >> 2, wc = w & 3;

#pragma unroll
  for (int i = 0; i < 4; ++i)
#pragma unroll
    for (int j = 0; j < NF; ++j) acc[i][j] = (f32x4){0.f, 0.f, 0.f, 0.f};

  stage_half<BN>(Abase, Bbase, S, 0, 0, 0, w, lane);
  stage_half<BN>(Abase, Bbase, S, 0, 1, 0, w, lane);

  for (int t = 0; t < 32; ++t) {
    int bf = t & 1, tb = bf ^ 1;
    int ts = (t < 31) ? t + 1 : 31;
#pragma unroll
    for (int ks = 0; ks < 2; ++ks) {
      stage_half<BN>(Abase, Bbase, S, tb, ks, ts, w, lane);
      if constexpr (LB == 3)
        asm volatile("s_waitcnt vmcnt(8)" ::: "memory");
      else
        asm volatile("s_waitcnt vmcnt(6)" ::: "memory");
      __builtin_amdgcn_s_barrier();
      const __bf16* SA = &S->A[bf][ks][0][0];
      const __bf16* SB = &S->B[bf][ks][0][0];
      bf16x8 af[4], bfr[NF];
#pragma unroll
      for (int nf = 0; nf < NF; ++nf) {
        int row = wc * (BN / 4) + nf * 16 + ln15;
        bfr[nf] = *fragp(SB, row, g);
      }
#pragma unroll
      for (int mf = 0; mf < 4; ++mf) {
        int row = wr * 64 + mf * 16 + ln15;
        af[mf] = *fragp(SA, row, g);
      }
      __builtin_amdgcn_s_setprio(1);
#pragma unroll
      for (int mf = 0; mf < 4; ++mf)
#pragma unroll
        for (int nf = 0; nf < NF; ++nf)
          acc[mf][nf] = MFMA_BF16(af[mf], bfr[nf], acc[mf][nf]);
      __builtin_amdgcn_s_setprio(0);
    }
  }
  asm volatile("s_waitcnt vmcnt(0)" ::: "memory");
}

// Output GEMM: A = attn_g bf16 [4096][2048], Bt = wout_t [2048][2048] -> f32. 256 blocks.
__global__ __launch_bounds__(512) void gemm_out128(const __bf16* __restrict__ A,
                                                   const __bf16* __restrict__ Bt,
                                                   float* __restrict__ out) {
  __shared__ __align__(1024) SmemG<256> S;
  int sblk = blockIdx.x;
  int x = sblk & 7, i = sblk >> 3;
  int m0 = i * 128;
  int n0 = x * 256;
  f32x4 acc[4][4];
  gemm128_core<256>(A + (size_t)m0 * 2048, Bt + (size_t)n0 * 2048, &S, acc);

  int tid = threadIdx.x;
  int w = tid >> 6, lane = tid & 63;
  int ln15 = lane & 15, g = lane >> 4;
  int wr = w >> 2, wc = w & 3;
#pragma unroll
  for (int mf = 0; mf < 4; ++mf)
#pragma unroll
    for (int nf = 0; nf < 4; ++nf)
#pragma unroll
      for (int rr = 0; rr < 4; ++rr) {
        int m = m0 + wr * 64 + mf * 16 + g * 4 + rr;
        int c = n0 + wc * 64 + nf * 16 + ln15;
        out[(size_t)m * NDIM + c] = acc[mf][nf][rr];
      }
}

// ---------------------------------------------------------------------------
// Flash attention R10: 512 threads / 8 waves, 128-row q-super-tiles paired
// (p, 15-p); per-wave math identical to R8 (swapped QK^T, fixed-max softmax
// M=12, in-register P, dual-q sharing K/V frags); double-buffered KV with
// counted vmcnt(4). Grid 256 = 32 bh x 8 pairs.
static __device__ __forceinline__ void softcap_p(const f32x4* accS, float (*p)[4],
                                                 float& l_r, int j0, int q0s,
                                                 bool diag, int ln15, int g) {
#pragma unroll
  for (int jt = 0; jt < 4; ++jt)
#pragma unroll
    for (int r = 0; r < 4; ++r) {
      float e2 = __expf(accS[jt][r] * 0.04f);
      float cap = 50.f - __fdividef(100.f, e2 + 1.f);  // 50*tanh(s/50)
      float pv = __expf(cap - 12.f);
      if (diag && (j0 + jt * 16 + g * 4 + r > q0s + ln15)) pv = 0.f;
      p[jt][r] = pv;
      l_r += pv;
    }
}

static __device__ __forceinline__ bf16x8 build_pa(const float (*p)[4], int c,
                                                  int lane_lo, int lane_hi, int g) {
  unsigned P0w0 = pack2_bf16(p[2 * c][0], p[2 * c][1]);
  unsigned P0w1 = pack2_bf16(p[2 * c][2], p[2 * c][3]);
  unsigned P1w0 = pack2_bf16(p[2 * c + 1][0], p[2 * c + 1][1]);
  unsigned P1w1 = pack2_bf16(p[2 * c + 1][2], p[2 * c + 1][3]);
  unsigned a0 = (unsigned)__shfl((int)P0w0, lane_lo);
  unsigned a1 = (unsigned)__shfl((int)P0w1, lane_lo);
  unsigned b0 = (unsigned)__shfl((int)P1w0, lane_lo);
  unsigned b1 = (unsigned)__shfl((int)P1w1, lane_lo);
  unsigned c0 = (unsigned)__shfl((int)P0w0, lane_hi);
  unsigned c1 = (unsigned)__shfl((int)P0w1, lane_hi);
  unsigned e0 = (unsigned)__shfl((int)P1w0, lane_hi);
  unsigned e1 = (unsigned)__shfl((int)P1w1, lane_hi);
  union { unsigned u[4]; bf16x8 v; } pu;
  pu.u[0] = (g < 2) ? a0 : b0;
  pu.u[1] = (g < 2) ? a1 : b1;
  pu.u[2] = (g < 2) ? c0 : e0;
  pu.u[3] = (g < 2) ? c1 : e1;
  return pu.v;
}

static __device__ __forceinline__ void attn_tile2(const __bf16* __restrict__ Kl,
                                                  const __bf16* __restrict__ Vl,
                                                  const bf16x8* qfh, const bf16x8* qfl,
                                                  f32x4* acc_h, f32x4* acc_l,
                                                  float& l_h, float& l_l,
                                                  int j0, int q0h, int q0l,
                                                  bool diag_h, bool diag_l,
                                                  bool do_hi, bool do_lo,
                                                  int ln15, int g) {
  f32x4 sh[4], sl[4];
#pragma unroll
  for (int jt = 0; jt < 4; ++jt) {
    sh[jt] = (f32x4){0.f, 0.f, 0.f, 0.f};
    sl[jt] = (f32x4){0.f, 0.f, 0.f, 0.f};
  }
  __builtin_amdgcn_s_setprio(1);
#pragma unroll
  for (int jt = 0; jt < 4; ++jt)
#pragma unroll
    for (int kc = 0; kc < 4; ++kc) {
      int row = jt * 16 + ln15;
      int bc = (kc * 64 + g * 16) ^ ((row & 7) << 4);
      bf16x8 kf = *reinterpret_cast<const bf16x8*>(Kl + row * 128 + (bc >> 1));
      if (do_hi) sh[jt] = MFMA_BF16(kf, qfh[kc], sh[jt]);
      if (do_lo) sl[jt] = MFMA_BF16(kf, qfl[kc], sl[jt]);
    }
  __builtin_amdgcn_s_setprio(0);
  float ph[4][4], pl[4][4];
  if (do_hi) softcap_p(sh, ph, l_h, j0, q0h, diag_h, ln15, g);
  if (do_lo) softcap_p(sl, pl, l_l, j0, q0l, diag_l, ln15, g);
  int lane_lo = ln15 + 32 * (g & 1);
  int lane_hi = lane_lo + 16;
#pragma unroll
  for (int c = 0; c < 2; ++c) {
    bf16x8 pah = build_pa(ph, c, lane_lo, lane_hi, g);
    bf16x8 pal = build_pa(pl, c, lane_lo, lane_hi, g);
    __builtin_amdgcn_s_setprio(1);
#pragma unroll
    for (int d0 = 0; d0 < 8; ++d0) {
      int d = d0 * 16 + ln15;
      int bc = (c * 64 + g * 16) ^ ((d & 7) << 4);
      bf16x8 vf = *reinterpret_cast<const bf16x8*>(Vl + d * 64 + (bc >> 1));
      if (do_hi) acc_h[d0] = MFMA_BF16(pah, vf, acc_h[d0]);
      if (do_lo) acc_l[d0] = MFMA_BF16(pal, vf, acc_l[d0]);
    }
    __builtin_amdgcn_s_setprio(0);
  }
}

__global__ __launch_bounds__(512, 2) void attn_kernel(const __bf16* __restrict__ qb,
                                                      const __bf16* __restrict__ kb,
                                                      const __bf16* __restrict__ vtb,
                                                      const float* __restrict__ gates,
                                                      __bf16* __restrict__ og) {
  __shared__ __align__(1024) __bf16 Kl[2][64 * 128];
  __shared__ __align__(1024) __bf16 Vl[2][128 * 64];
  int tid = threadIdx.x;
  int w = tid >> 6, lane = tid & 63;
  int ln15 = lane & 15, g = lane >> 4;
  int bx = blockIdx.x;
  int p = bx & 7, bh = bx >> 3;
  int hi = 15 - p, lo = p;  // 128-row q-super-tiles
  const __bf16* qh = qb + (size_t)bh * NSEQ * NDH;
  const __bf16* kh = kb + (size_t)bh * NSEQ * NDH;
  const __bf16* vh = vtb + (size_t)bh * NDH * NSEQ;

  int q0h = hi * 128 + w * 16;  // 8 waves cover the 128 rows of each set
  int q0l = lo * 128 + w * 16;
  bf16x8 qfh[4], qfl[4];
#pragma unroll
  for (int kc = 0; kc < 4; ++kc) {
    qfh[kc] = *reinterpret_cast<const bf16x8*>(qh + (size_t)(q0h + ln15) * NDH + kc * 32 + g * 8);
    qfl[kc] = *reinterpret_cast<const bf16x8*>(qh + (size_t)(q0l + ln15) * NDH + kc * 32 + g * 8);
  }

  f32x4 acc_h[8], acc_l[8];
#pragma unroll
  for (int d0 = 0; d0 < 8; ++d0) {
    acc_h[d0] = (f32x4){0.f, 0.f, 0.f, 0.f};
    acc_l[d0] = (f32x4){0.f, 0.f, 0.f, 0.f};
  }
  float l_h = 0.f, l_l = 0.f;

  // stage: 512 threads, 4 gload_lds16 each (2 K-granules + 2 V-granules);
  // linear LDS dest, inverse-swizzled global source (XOR involution).
  auto stage = [&](int t, int buf) {
    int j0 = t * 64;
#pragma unroll
    for (int c = 0; c < 2; ++c) {
      int gi = c * 512 + w * 64 + lane;
      int kr = gi >> 4, kcs = gi & 15;
      int kc_ = kcs ^ (kr & 7);
      gload_lds16(kh + (size_t)(j0 + kr) * NDH + kc_ * 8,
                  &Kl[buf][(c * 512 + w * 64) * 8]);
      int vr = gi >> 3, vcs = gi & 7;
      int vc_ = vcs ^ (vr & 7);
      gload_lds16(vh + (size_t)vr * NSEQ + j0 + vc_ * 8,
                  &Vl[buf][(c * 512 + w * 64) * 8]);
    }
  };

  int ntiles = 2 * hi + 2;  // 64-key tiles covering keys < (hi+1)*128
  stage(0, 0);
  for (int t = 0; t < ntiles; ++t) {
    int cb = t & 1;
    if (t < ntiles - 1) {
      stage(t + 1, cb ^ 1);
      asm volatile("s_waitcnt vmcnt(4)" ::: "memory");  // retire tile t's 4
    } else {
      asm volatile("s_waitcnt vmcnt(0)" ::: "memory");
    }
    __builtin_amdgcn_s_barrier();
    int j0 = t * 64;
    bool do_hi = (j0 <= q0h + 15);
    bool do_lo = (j0 <= q0l + 15);
    attn_tile2(&Kl[cb][0], &Vl[cb][0], qfh, qfl, acc_h, acc_l, l_h, l_l,
               j0, q0h, q0l, j0 + 63 > q0h, j0 + 63 > q0l, do_hi, do_lo,
               ln15, g);
    __builtin_amdgcn_s_barrier();  // all waves done reading cb before overwrite
  }

  l_h += __shfl_xor(l_h, 16); l_h += __shfl_xor(l_h, 32);
  l_l += __shfl_xor(l_l, 16); l_l += __shfl_xor(l_l, 32);

  int b = bh >> 4, h = bh & 15;
#pragma unroll
  for (int set = 0; set < 2; ++set) {
    int q0s = set ? q0l : q0h;
    f32x4* acc = set ? acc_l : acc_h;
    float lr = set ? l_l : l_h;
    float gv[4];
#pragma unroll
    for (int r = 0; r < 4; ++r) {
      float lv = __shfl(lr, g * 4 + r);
      int row = q0s + g * 4 + r;
      gv[r] = gates[(size_t)bh * NSEQ + row] / lv;
    }
#pragma unroll
    for (int d0 = 0; d0 < 8; ++d0)
#pragma unroll
      for (int r = 0; r < 4; ++r) {
        int row = q0s + g * 4 + r;
        og[((size_t)(b * NSEQ + row)) * NDIM + h * NDH + d0 * 16 + ln15] =
            (__bf16)(acc[d0][r] * gv[r]);
      }
  }
}

// ---------------------------------------------------------------------------
extern "C" void kernel_launch(void* const* d_in, const int* in_sizes, int n_in,
                              void* d_out, int out_size, void* d_ws, size_t ws_size,
                              hipStream_t stream) {
  const float* x = (const float*)d_in[0];
  const float* w_qkv = (const float*)d_in[1];
  const float* w_gates = (const float*)d_in[2];
  const float* w_out = (const float*)d_in[3];
  float* out = (float*)d_out;
  char* ws = (char*)d_ws;

  __bf16* x_bf   = (__bf16*)(ws + 0);          // 16,777,216
  __bf16* wqkv_t = (__bf16*)(ws + 16777216);   // 25,165,824
  __bf16* wout_t = (__bf16*)(ws + 41943040);   // 8,388,608
  __bf16* q_buf  = (__bf16*)(ws + 50331648);   // 16,777,216
  __bf16* k_buf  = (__bf16*)(ws + 67108864);   // 16,777,216
  __bf16* vt_buf = (__bf16*)(ws + 83886080);   // 16,777,216
  float*  gates  = (float*)(ws + 100663296);   // 262,144
  __bf16* attn_g = (__bf16*)(ws + 100925440);  // 16,777,216

  cvt_gates_kernel<<<4096, 256, 0, stream>>>(x, w_gates, x_bf, gates);
  transpose_cvt_kernel<<<dim3(192, 64), 256, 0, stream>>>(w_qkv, wqkv_t, 2048, 6144);
  transpose_cvt_kernel<<<dim3(64, 64), 256, 0, stream>>>(w_out, wout_t, 2048, 2048);
  gemm_qkv256b<<<256, 512, 0, stream>>>(x_bf, wqkv_t, q_buf, k_buf, vt_buf);
  attn_kernel<<<256, 512, 0, stream>>>(q_buf, k_buf, vt_buf, gates, attn_g);
  gemm_out128<<<256, 512, 0, stream>>>(attn_g, wout_t, out);
}

// Round 11
// 342.386 us; speedup vs baseline: 1.1139x; 1.1139x over previous
//
#include <hip/hip_runtime.h>
#include <hip/hip_bf16.h>
#include <math.h>

// ---------------------------------------------------------------------------
// Gated causal attention block, bf16 MFMA pipeline. B=2,N=2048,DIM=2048,H=16,DH=128.
// R11: consolidation. R9/R10 both showed attn is latency-bound and the R8
//     structure (2 independent 256-thr blocks/CU, dual-q pairing, counted
//     vmcnt dbuf) is the best measured (129us) -> reverted to it exactly.
//     Kept R10's fused cvt+gates prologue (saves one 67MB x pass). Softcap
//     algebra fused: p = 2^(54.8224 - 144.2695*rcp(e2+1)), e2 = 2^(0.0577*s)
//     -- exact same function, ~25% fewer softmax ops. GEMMs unchanged (R8).
// ---------------------------------------------------------------------------

typedef __attribute__((ext_vector_type(8))) __bf16 bf16x8;
typedef __attribute__((ext_vector_type(4))) __bf16 bf16x4;
typedef __attribute__((ext_vector_type(4))) float f32x4;

#define MFMA_BF16(a, b, c) __builtin_amdgcn_mfma_f32_16x16x32_bf16((a), (b), (c), 0, 0, 0)

#define NB 2
#define NSEQ 2048
#define NDIM 2048
#define NH 16
#define NDH 128
#define SCALE_Q 0.08838834764831845f /* 128^-0.5 */

#define AS1 __attribute__((address_space(1)))
#define AS3 __attribute__((address_space(3)))
static __device__ __forceinline__ void gload_lds16(const void* g, void* l) {
  __builtin_amdgcn_global_load_lds((AS1 const void*)g, (AS3 void*)l, 16, 0, 0);
}

static __device__ __forceinline__ unsigned pack2_bf16(float a, float b) {
  unsigned short ua = __builtin_bit_cast(unsigned short, (__bf16)a);
  unsigned short ub = __builtin_bit_cast(unsigned short, (__bf16)b);
  return (unsigned)ua | ((unsigned)ub << 16);
}

// ---------------------------------------------------------------------------
// Fused x->bf16 conversion + gates (R10 win). One block per row (b*N+n).
__global__ __launch_bounds__(256) void cvt_gates_kernel(const float* __restrict__ x,
                                                        const float* __restrict__ wg,
                                                        __bf16* __restrict__ x_bf,
                                                        float* __restrict__ gates) {
  __shared__ float red[64];
  int row = blockIdx.x;
  int tid = threadIdx.x;
  const float* xr = x + (size_t)row * NDIM;
  int k0 = tid * 8;
  float4 v0 = *reinterpret_cast<const float4*>(xr + k0);
  float4 v1 = *reinterpret_cast<const float4*>(xr + k0 + 4);
  float vv[8] = {v0.x, v0.y, v0.z, v0.w, v1.x, v1.y, v1.z, v1.w};
  union { bf16x8 v; } o;
#pragma unroll
  for (int j = 0; j < 8; ++j) o.v[j] = (__bf16)vv[j];
  *reinterpret_cast<bf16x8*>(x_bf + (size_t)row * NDIM + k0) = o.v;

  float acc[16];
#pragma unroll
  for (int h = 0; h < 16; ++h) acc[h] = 0.f;
#pragma unroll
  for (int j = 0; j < 8; ++j) {
    const float* wr = wg + (size_t)(k0 + j) * NH;
#pragma unroll
    for (int h = 0; h < 16; ++h) acc[h] += vv[j] * wr[h];
  }
  int w = tid >> 6, lane = tid & 63;
#pragma unroll
  for (int h = 0; h < 16; ++h) {
    float v = acc[h];
#pragma unroll
    for (int off = 32; off; off >>= 1) v += __shfl_down(v, off);
    if (lane == 0) red[w * 16 + h] = v;
  }
  __syncthreads();
  if (tid < 16) {
    float s = red[tid] + red[16 + tid] + red[32 + tid] + red[48 + tid];
    int b = row >> 11, n = row & 2047;
    gates[((size_t)(b * NH + tid)) * NSEQ + n] = 1.f / (1.f + expf(-s));
  }
}

// in: f32 [K][C] row-major -> out: bf16 [C][K] row-major
__global__ __launch_bounds__(256) void transpose_cvt_kernel(const float* __restrict__ in,
                                                            __bf16* __restrict__ out,
                                                            int K, int C) {
  __shared__ float tile[32][33];
  int c0 = blockIdx.x * 32, k0 = blockIdx.y * 32;
  int t = threadIdx.x;
  int lc = t & 31, lr = t >> 5;
#pragma unroll
  for (int rr = 0; rr < 4; ++rr)
    tile[lr + rr * 8][lc] = in[(size_t)(k0 + lr + rr * 8) * C + c0 + lc];
  __syncthreads();
#pragma unroll
  for (int rr = 0; rr < 4; ++rr)
    out[(size_t)(c0 + lr + rr * 8) * K + k0 + lc] = (__bf16)tile[lc][lr + rr * 8];
}

// ---------------------------------------------------------------------------
// qkv core (unchanged R8): BM=256, BN=384, BK=32, 8 waves, LDS ring-of-3.
struct SmemQ {
  __bf16 T[3][640][32];  // 120 KiB
};

static __device__ __forceinline__ const bf16x8* fragq(const __bf16* base, int row, int g) {
  return (const bf16x8*)(base + row * 32 + (g ^ ((row >> 1) & 3)) * 8);
}

__global__ __launch_bounds__(512, 2) void gemm_qkv256b(const __bf16* __restrict__ A,
                                                       const __bf16* __restrict__ Bt,
                                                       __bf16* __restrict__ qb,
                                                       __bf16* __restrict__ kb,
                                                       __bf16* __restrict__ vtb) {
  __shared__ __align__(1024) SmemQ S;
  int sblk = blockIdx.x;
  int x = sblk & 7, i = sblk >> 3;
  int m0 = (i >> 1) * 256;
  int n0 = (2 * x + (i & 1)) * 384;
  const __bf16* Ab = A + (size_t)m0 * 2048;
  const __bf16* Bb = Bt + (size_t)n0 * 2048;

  int tid = threadIdx.x;
  int w = tid >> 6, lane = tid & 63;
  int ln15 = lane & 15, g = lane >> 4;
  int wr = w >> 2, wc = w & 3;
  int lr4 = lane >> 2, l3 = lane & 3;

  auto stage = [&](int kt, int rb) {
#pragma unroll
    for (int j = 0; j < 5; ++j) {
      int k = w + 8 * j;
      int row = k * 16 + lr4;
      int sg = l3 ^ ((row >> 1) & 3);
      const __bf16* src = (k < 16)
          ? Ab + (size_t)row * 2048 + kt * 32 + sg * 8
          : Bb + (size_t)(row - 256) * 2048 + kt * 32 + sg * 8;
      gload_lds16(src, &S.T[rb][k * 16][0]);
    }
  };

  f32x4 acc[8][6];
#pragma unroll
  for (int a = 0; a < 8; ++a)
#pragma unroll
    for (int nf = 0; nf < 6; ++nf) acc[a][nf] = (f32x4){0.f, 0.f, 0.f, 0.f};

  stage(0, 0);
  stage(1, 1);
  for (int t = 0; t < 64; ++t) {
    int rb = t % 3;
    asm volatile("s_waitcnt vmcnt(5)" ::: "memory");
    __builtin_amdgcn_s_barrier();
    asm volatile("" ::: "memory");
    int ts = (t < 62) ? t + 2 : 63;
    stage(ts, (t + 2) % 3);
    const __bf16* Sb = &S.T[rb][0][0];
    bf16x8 bfr[6];
#pragma unroll
    for (int nf = 0; nf < 6; ++nf) {
      int row = 256 + wc * 96 + nf * 16 + ln15;
      bfr[nf] = *fragq(Sb, row, g);
    }
#pragma unroll
    for (int mh = 0; mh < 2; ++mh) {
      bf16x8 af[4];
#pragma unroll
      for (int a = 0; a < 4; ++a) {
        int row = wr * 128 + (mh * 4 + a) * 16 + ln15;
        af[a] = *fragq(Sb, row, g);
      }
      __builtin_amdgcn_s_setprio(1);
#pragma unroll
      for (int a = 0; a < 4; ++a)
#pragma unroll
        for (int nf = 0; nf < 6; ++nf)
          acc[mh * 4 + a][nf] = MFMA_BF16(af[a], bfr[nf], acc[mh * 4 + a][nf]);
      __builtin_amdgcn_s_setprio(0);
    }
  }
  asm volatile("s_waitcnt vmcnt(0)" ::: "memory");

#pragma unroll
  for (int nf = 0; nf < 6; ++nf) {
    int ng = n0 + wc * 96 + nf * 16 + ln15;
    int qkv = ng >> 11;
    int h = (ng >> 7) & 15;
    int d = ng & 127;
#pragma unroll
    for (int mf = 0; mf < 8; ++mf)
#pragma unroll
      for (int rr = 0; rr < 4; ++rr) {
        int m = m0 + wr * 128 + mf * 16 + g * 4 + rr;
        int b = m >> 11, n = m & 2047;
        int bh = b * NH + h;
        float v = acc[mf][nf][rr];
        if (qkv == 0)
          qb[((size_t)bh * NSEQ + n) * NDH + d] = (__bf16)(v * SCALE_Q);
        else if (qkv == 1)
          kb[((size_t)bh * NSEQ + n) * NDH + d] = (__bf16)v;
        else
          vtb[((size_t)bh * NDH + d) * NSEQ + n] = (__bf16)v;
      }
  }
}

// ---------------------------------------------------------------------------
// gemm_out core (unchanged): BM=128 x BN=256, BK=64, 8 waves.
template <int BN> struct SmemG {
  __bf16 A[2][2][128][32];
  __bf16 B[2][2][BN][32];
};

template <int BN>
static __device__ __forceinline__ void stage_half(const __bf16* __restrict__ Ab,
                                                  const __bf16* __restrict__ Bb,
                                                  SmemG<BN>* S, int buf, int ks,
                                                  int kt, int w, int lane) {
  constexpr int LB = BN / 128;
  {
    int gid = w * 64 + lane;
    int row = gid >> 2, gc = gid & 3;
    int sg = gc ^ ((row >> 1) & 3);
    gload_lds16(Ab + (size_t)row * 2048 + kt * 64 + ks * 32 + sg * 8,
                &S->A[buf][ks][0][0] + (size_t)(w * 64) * 8);
  }
#pragma unroll
  for (int j = 0; j < LB; ++j) {
    int gid = j * 512 + w * 64 + lane;
    int row = gid >> 2, gc = gid & 3;
    int sg = gc ^ ((row >> 1) & 3);
    gload_lds16(Bb + (size_t)row * 2048 + kt * 64 + ks * 32 + sg * 8,
                &S->B[buf][ks][0][0] + (size_t)(j * 512 + w * 64) * 8);
  }
}

static __device__ __forceinline__ const bf16x8* fragp(const __bf16* base, int row, int g) {
  return (const bf16x8*)(base + row * 32 + (g ^ ((row >> 1) & 3)) * 8);
}

template <int BN>
static __device__ __forceinline__ void gemm128_core(const __bf16* __restrict__ Abase,
                                                    const __bf16* __restrict__ Bbase,
                                                    SmemG<BN>* S,
                                                    f32x4 (*acc)[BN / 64]) {
  constexpr int NF = BN / 64;
  constexpr int LB = BN / 128;
  int tid = threadIdx.x;
  int w = tid >> 6, lane = tid & 63;
  int ln15 = lane & 15, g = lane >> 4;
  int wr = w >> 2, wc = w & 3;

#pragma unroll
  for (int i = 0; i < 4; ++i)
#pragma unroll
    for (int j = 0; j < NF; ++j) acc[i][j] = (f32x4){0.f, 0.f, 0.f, 0.f};

  stage_half<BN>(Abase, Bbase, S, 0, 0, 0, w, lane);
  stage_half<BN>(Abase, Bbase, S, 0, 1, 0, w, lane);

  for (int t = 0; t < 32; ++t) {
    int bf = t & 1, tb = bf ^ 1;
    int ts = (t < 31) ? t + 1 : 31;
#pragma unroll
    for (int ks = 0; ks < 2; ++ks) {
      stage_half<BN>(Abase, Bbase, S, tb, ks, ts, w, lane);
      if constexpr (LB == 3)
        asm volatile("s_waitcnt vmcnt(8)" ::: "memory");
      else
        asm volatile("s_waitcnt vmcnt(6)" ::: "memory");
      __builtin_amdgcn_s_barrier();
      const __bf16* SA = &S->A[bf][ks][0][0];
      const __bf16* SB = &S->B[bf][ks][0][0];
      bf16x8 af[4], bfr[NF];
#pragma unroll
      for (int nf = 0; nf < NF; ++nf) {
        int row = wc * (BN / 4) + nf * 16 + ln15;
        bfr[nf] = *fragp(SB, row, g);
      }
#pragma unroll
      for (int mf = 0; mf < 4; ++mf) {
        int row = wr * 64 + mf * 16 + ln15;
        af[mf] = *fragp(SA, row, g);
      }
      __builtin_amdgcn_s_setprio(1);
#pragma unroll
      for (int mf = 0; mf < 4; ++mf)
#pragma unroll
        for (int nf = 0; nf < NF; ++nf)
          acc[mf][nf] = MFMA_BF16(af[mf], bfr[nf], acc[mf][nf]);
      __builtin_amdgcn_s_setprio(0);
    }
  }
  asm volatile("s_waitcnt vmcnt(0)" ::: "memory");
}

// Output GEMM: A = attn_g bf16 [4096][2048], Bt = wout_t [2048][2048] -> f32. 256 blocks.
__global__ __launch_bounds__(512) void gemm_out128(const __bf16* __restrict__ A,
                                                   const __bf16* __restrict__ Bt,
                                                   float* __restrict__ out) {
  __shared__ __align__(1024) SmemG<256> S;
  int sblk = blockIdx.x;
  int x = sblk & 7, i = sblk >> 3;
  int m0 = i * 128;
  int n0 = x * 256;
  f32x4 acc[4][4];
  gemm128_core<256>(A + (size_t)m0 * 2048, Bt + (size_t)n0 * 2048, &S, acc);

  int tid = threadIdx.x;
  int w = tid >> 6, lane = tid & 63;
  int ln15 = lane & 15, g = lane >> 4;
  int wr = w >> 2, wc = w & 3;
#pragma unroll
  for (int mf = 0; mf < 4; ++mf)
#pragma unroll
    for (int nf = 0; nf < 4; ++nf)
#pragma unroll
      for (int rr = 0; rr < 4; ++rr) {
        int m = m0 + wr * 64 + mf * 16 + g * 4 + rr;
        int c = n0 + wc * 64 + nf * 16 + ln15;
        out[(size_t)m * NDIM + c] = acc[mf][nf][rr];
      }
}

// ---------------------------------------------------------------------------
// Flash attention (exact R8 structure): 256 thr / 4 waves, dual-q (lo,31-lo),
// 512 blocks = 2/CU, dbuf KV + counted vmcnt(8). Fixed-max softmax M=12.
// Softcap fused: p = exp(50*tanh(s/50)-12) = 2^(54.8224 - 144.2695*rcp(e2+1)),
// e2 = 2^(s*0.0577078) -- same function, fewer ops.
static __device__ __forceinline__ void softcap_p(const f32x4* accS, float (*p)[4],
                                                 float& l_r, int j0, int q0s,
                                                 bool diag, int ln15, int g) {
#pragma unroll
  for (int jt = 0; jt < 4; ++jt)
#pragma unroll
    for (int r = 0; r < 4; ++r) {
      float e2 = __builtin_amdgcn_exp2f(accS[jt][r] * 0.057707801635558536f);
      float rc = __builtin_amdgcn_rcpf(e2 + 1.f);
      float pv = __builtin_amdgcn_exp2f(fmaf(rc, -144.26950408889634f, 54.82241155378061f));
      if (diag && (j0 + jt * 16 + g * 4 + r > q0s + ln15)) pv = 0.f;
      p[jt][r] = pv;
      l_r += pv;
    }
}

static __device__ __forceinline__ bf16x8 build_pa(const float (*p)[4], int c,
                                                  int lane_lo, int lane_hi, int g) {
  unsigned P0w0 = pack2_bf16(p[2 * c][0], p[2 * c][1]);
  unsigned P0w1 = pack2_bf16(p[2 * c][2], p[2 * c][3]);
  unsigned P1w0 = pack2_bf16(p[2 * c + 1][0], p[2 * c + 1][1]);
  unsigned P1w1 = pack2_bf16(p[2 * c + 1][2], p[2 * c + 1][3]);
  unsigned a0 = (unsigned)__shfl((int)P0w0, lane_lo);
  unsigned a1 = (unsigned)__shfl((int)P0w1, lane_lo);
  unsigned b0 = (unsigned)__shfl((int)P1w0, lane_lo);
  unsigned b1 = (unsigned)__shfl((int)P1w1, lane_lo);
  unsigned c0 = (unsigned)__shfl((int)P0w0, lane_hi);
  unsigned c1 = (unsigned)__shfl((int)P0w1, lane_hi);
  unsigned e0 = (unsigned)__shfl((int)P1w0, lane_hi);
  unsigned e1 = (unsigned)__shfl((int)P1w1, lane_hi);
  union { unsigned u[4]; bf16x8 v; } pu;
  pu.u[0] = (g < 2) ? a0 : b0;
  pu.u[1] = (g < 2) ? a1 : b1;
  pu.u[2] = (g < 2) ? c0 : e0;
  pu.u[3] = (g < 2) ? c1 : e1;
  return pu.v;
}

static __device__ __forceinline__ void attn_tile2(const __bf16* __restrict__ Kl,
                                                  const __bf16* __restrict__ Vl,
                                                  const bf16x8* qfh, const bf16x8* qfl,
                                                  f32x4* acc_h, f32x4* acc_l,
                                                  float& l_h, float& l_l,
                                                  int j0, int q0h, int q0l,
                                                  bool diag_h, bool diag_l, bool do_lo,
                                                  int ln15, int g) {
  f32x4 sh[4], sl[4];
#pragma unroll
  for (int jt = 0; jt < 4; ++jt) {
    sh[jt] = (f32x4){0.f, 0.f, 0.f, 0.f};
    sl[jt] = (f32x4){0.f, 0.f, 0.f, 0.f};
  }
  __builtin_amdgcn_s_setprio(1);
#pragma unroll
  for (int jt = 0; jt < 4; ++jt)
#pragma unroll
    for (int kc = 0; kc < 4; ++kc) {
      int row = jt * 16 + ln15;
      int bc = (kc * 64 + g * 16) ^ ((row & 7) << 4);
      bf16x8 kf = *reinterpret_cast<const bf16x8*>(Kl + row * 128 + (bc >> 1));
      sh[jt] = MFMA_BF16(kf, qfh[kc], sh[jt]);
      if (do_lo) sl[jt] = MFMA_BF16(kf, qfl[kc], sl[jt]);
    }
  __builtin_amdgcn_s_setprio(0);
  float ph[4][4], pl[4][4];
  softcap_p(sh, ph, l_h, j0, q0h, diag_h, ln15, g);
  if (do_lo) softcap_p(sl, pl, l_l, j0, q0l, diag_l, ln15, g);
  int lane_lo = ln15 + 32 * (g & 1);
  int lane_hi = lane_lo + 16;
#pragma unroll
  for (int c = 0; c < 2; ++c) {
    bf16x8 pah = build_pa(ph, c, lane_lo, lane_hi, g);
    bf16x8 pal = build_pa(pl, c, lane_lo, lane_hi, g);
    __builtin_amdgcn_s_setprio(1);
#pragma unroll
    for (int d0 = 0; d0 < 8; ++d0) {
      int d = d0 * 16 + ln15;
      int bc = (c * 64 + g * 16) ^ ((d & 7) << 4);
      bf16x8 vf = *reinterpret_cast<const bf16x8*>(Vl + d * 64 + (bc >> 1));
      acc_h[d0] = MFMA_BF16(pah, vf, acc_h[d0]);
      if (do_lo) acc_l[d0] = MFMA_BF16(pal, vf, acc_l[d0]);
    }
    __builtin_amdgcn_s_setprio(0);
  }
}

__global__ __launch_bounds__(256, 2) void attn_kernel(const __bf16* __restrict__ qb,
                                                      const __bf16* __restrict__ kb,
                                                      const __bf16* __restrict__ vtb,
                                                      const float* __restrict__ gates,
                                                      __bf16* __restrict__ og) {
  __shared__ __align__(1024) __bf16 Kl[2][64 * 128];
  __shared__ __align__(1024) __bf16 Vl[2][128 * 64];
  int tid = threadIdx.x;
  int w = tid >> 6, lane = tid & 63;
  int ln15 = lane & 15, g = lane >> 4;
  int bx = blockIdx.x;
  int lo = bx & 15, bh = bx >> 4;
  int hi = 31 - lo;
  const __bf16* qh = qb + (size_t)bh * NSEQ * NDH;
  const __bf16* kh = kb + (size_t)bh * NSEQ * NDH;
  const __bf16* vh = vtb + (size_t)bh * NDH * NSEQ;

  int q0h = hi * 64 + w * 16;
  int q0l = lo * 64 + w * 16;
  bf16x8 qfh[4], qfl[4];
#pragma unroll
  for (int kc = 0; kc < 4; ++kc) {
    qfh[kc] = *reinterpret_cast<const bf16x8*>(qh + (size_t)(q0h + ln15) * NDH + kc * 32 + g * 8);
    qfl[kc] = *reinterpret_cast<const bf16x8*>(qh + (size_t)(q0l + ln15) * NDH + kc * 32 + g * 8);
  }

  f32x4 acc_h[8], acc_l[8];
#pragma unroll
  for (int d0 = 0; d0 < 8; ++d0) {
    acc_h[d0] = (f32x4){0.f, 0.f, 0.f, 0.f};
    acc_l[d0] = (f32x4){0.f, 0.f, 0.f, 0.f};
  }
  float l_h = 0.f, l_l = 0.f;

  auto stage = [&](int t, int buf) {
    int j0 = t * 64;
#pragma unroll
    for (int i = 0; i < 4; ++i) {
      int gi = (i * 4 + w) * 64 + lane;
      int kr = gi >> 4, kcs = gi & 15;
      int kc_ = kcs ^ (kr & 7);
      gload_lds16(kh + (size_t)(j0 + kr) * NDH + kc_ * 8, &Kl[buf][(i * 4 + w) * 512]);
      int vr = gi >> 3, vcs = gi & 7;
      int vc_ = vcs ^ (vr & 7);
      gload_lds16(vh + (size_t)vr * NSEQ + j0 + vc_ * 8, &Vl[buf][(i * 4 + w) * 512]);
    }
  };

  stage(0, 0);
  for (int t = 0; t <= hi; ++t) {
    int cb = t & 1;
    if (t < hi) {
      stage(t + 1, cb ^ 1);
      asm volatile("s_waitcnt vmcnt(8)" ::: "memory");
    } else {
      asm volatile("s_waitcnt vmcnt(0)" ::: "memory");
    }
    __builtin_amdgcn_s_barrier();
    attn_tile2(&Kl[cb][0], &Vl[cb][0], qfh, qfl, acc_h, acc_l, l_h, l_l,
               t * 64, q0h, q0l, t == hi, t == lo, t <= lo, ln15, g);
    __builtin_amdgcn_s_barrier();
  }

  l_h += __shfl_xor(l_h, 16); l_h += __shfl_xor(l_h, 32);
  l_l += __shfl_xor(l_l, 16); l_l += __shfl_xor(l_l, 32);

  int b = bh >> 4, h = bh & 15;
#pragma unroll
  for (int set = 0; set < 2; ++set) {
    int q0s = set ? q0l : q0h;
    f32x4* acc = set ? acc_l : acc_h;
    float lr = set ? l_l : l_h;
    float gv[4];
#pragma unroll
    for (int r = 0; r < 4; ++r) {
      float lv = __shfl(lr, g * 4 + r);
      int row = q0s + g * 4 + r;
      gv[r] = gates[(size_t)bh * NSEQ + row] / lv;
    }
#pragma unroll
    for (int d0 = 0; d0 < 8; ++d0)
#pragma unroll
      for (int r = 0; r < 4; ++r) {
        int row = q0s + g * 4 + r;
        og[((size_t)(b * NSEQ + row)) * NDIM + h * NDH + d0 * 16 + ln15] =
            (__bf16)(acc[d0][r] * gv[r]);
      }
  }
}

// ---------------------------------------------------------------------------
extern "C" void kernel_launch(void* const* d_in, const int* in_sizes, int n_in,
                              void* d_out, int out_size, void* d_ws, size_t ws_size,
                              hipStream_t stream) {
  const float* x = (const float*)d_in[0];
  const float* w_qkv = (const float*)d_in[1];
  const float* w_gates = (const float*)d_in[2];
  const float* w_out = (const float*)d_in[3];
  float* out = (float*)d_out;
  char* ws = (char*)d_ws;

  __bf16* x_bf   = (__bf16*)(ws + 0);          // 16,777,216
  __bf16* wqkv_t = (__bf16*)(ws + 16777216);   // 25,165,824
  __bf16* wout_t = (__bf16*)(ws + 41943040);   // 8,388,608
  __bf16* q_buf  = (__bf16*)(ws + 50331648);   // 16,777,216
  __bf16* k_buf  = (__bf16*)(ws + 67108864);   // 16,777,216
  __bf16* vt_buf = (__bf16*)(ws + 83886080);   // 16,777,216
  float*  gates  = (float*)(ws + 100663296);   // 262,144
  __bf16* attn_g = (__bf16*)(ws + 100925440);  // 16,777,216

  cvt_gates_kernel<<<4096, 256, 0, stream>>>(x, w_gates, x_bf, gates);
  transpose_cvt_kernel<<<dim3(192, 64), 256, 0, stream>>>(w_qkv, wqkv_t, 2048, 6144);
  transpose_cvt_kernel<<<dim3(64, 64), 256, 0, stream>>>(w_out, wout_t, 2048, 2048);
  gemm_qkv256b<<<256, 512, 0, stream>>>(x_bf, wqkv_t, q_buf, k_buf, vt_buf);
  attn_kernel<<<512, 256, 0, stream>>>(q_buf, k_buf, vt_buf, gates, attn_g);
  gemm_out128<<<256, 512, 0, stream>>>(attn_g, wout_t, out);
}

// Round 12
// 340.951 us; speedup vs baseline: 1.1186x; 1.0042x over previous
//
#include <hip/hip_runtime.h>
#include <hip/hip_bf16.h>
#include <math.h>

// ---------------------------------------------------------------------------
// Gated causal attention block, bf16 MFMA pipeline. B=2,N=2048,DIM=2048,H=16,DH=128.
// R12: prefetch DEPTH on the staging-bound GEMMs. R11 analysis: my "12.5
//     B/cy/CU fill invariant" was the shared depth-1 flaw of my schedules
//     (m201 gets ~20, hipBLASLt ~26 on this HW). qkv: ring-3 -> ring-4
//     (160KB LDS, vmcnt(10), 2-phase lookahead). gemm_out: rebuilt on the
//     ring template, BM=256xBN=128xBK=32, ring-6 (144KB, vmcnt(12),
//     4-phase lookahead), grid 256. attn + prologue unchanged from R11.
// ---------------------------------------------------------------------------

typedef __attribute__((ext_vector_type(8))) __bf16 bf16x8;
typedef __attribute__((ext_vector_type(4))) __bf16 bf16x4;
typedef __attribute__((ext_vector_type(4))) float f32x4;

#define MFMA_BF16(a, b, c) __builtin_amdgcn_mfma_f32_16x16x32_bf16((a), (b), (c), 0, 0, 0)

#define NB 2
#define NSEQ 2048
#define NDIM 2048
#define NH 16
#define NDH 128
#define SCALE_Q 0.08838834764831845f /* 128^-0.5 */

#define AS1 __attribute__((address_space(1)))
#define AS3 __attribute__((address_space(3)))
static __device__ __forceinline__ void gload_lds16(const void* g, void* l) {
  __builtin_amdgcn_global_load_lds((AS1 const void*)g, (AS3 void*)l, 16, 0, 0);
}

static __device__ __forceinline__ unsigned pack2_bf16(float a, float b) {
  unsigned short ua = __builtin_bit_cast(unsigned short, (__bf16)a);
  unsigned short ub = __builtin_bit_cast(unsigned short, (__bf16)b);
  return (unsigned)ua | ((unsigned)ub << 16);
}

// ---------------------------------------------------------------------------
// Fused x->bf16 conversion + gates. One block per row (b*N+n).
__global__ __launch_bounds__(256) void cvt_gates_kernel(const float* __restrict__ x,
                                                        const float* __restrict__ wg,
                                                        __bf16* __restrict__ x_bf,
                                                        float* __restrict__ gates) {
  __shared__ float red[64];
  int row = blockIdx.x;
  int tid = threadIdx.x;
  const float* xr = x + (size_t)row * NDIM;
  int k0 = tid * 8;
  float4 v0 = *reinterpret_cast<const float4*>(xr + k0);
  float4 v1 = *reinterpret_cast<const float4*>(xr + k0 + 4);
  float vv[8] = {v0.x, v0.y, v0.z, v0.w, v1.x, v1.y, v1.z, v1.w};
  union { bf16x8 v; } o;
#pragma unroll
  for (int j = 0; j < 8; ++j) o.v[j] = (__bf16)vv[j];
  *reinterpret_cast<bf16x8*>(x_bf + (size_t)row * NDIM + k0) = o.v;

  float acc[16];
#pragma unroll
  for (int h = 0; h < 16; ++h) acc[h] = 0.f;
#pragma unroll
  for (int j = 0; j < 8; ++j) {
    const float* wr = wg + (size_t)(k0 + j) * NH;
#pragma unroll
    for (int h = 0; h < 16; ++h) acc[h] += vv[j] * wr[h];
  }
  int w = tid >> 6, lane = tid & 63;
#pragma unroll
  for (int h = 0; h < 16; ++h) {
    float v = acc[h];
#pragma unroll
    for (int off = 32; off; off >>= 1) v += __shfl_down(v, off);
    if (lane == 0) red[w * 16 + h] = v;
  }
  __syncthreads();
  if (tid < 16) {
    float s = red[tid] + red[16 + tid] + red[32 + tid] + red[48 + tid];
    int b = row >> 11, n = row & 2047;
    gates[((size_t)(b * NH + tid)) * NSEQ + n] = 1.f / (1.f + expf(-s));
  }
}

// in: f32 [K][C] row-major -> out: bf16 [C][K] row-major
__global__ __launch_bounds__(256) void transpose_cvt_kernel(const float* __restrict__ in,
                                                            __bf16* __restrict__ out,
                                                            int K, int C) {
  __shared__ float tile[32][33];
  int c0 = blockIdx.x * 32, k0 = blockIdx.y * 32;
  int t = threadIdx.x;
  int lc = t & 31, lr = t >> 5;
#pragma unroll
  for (int rr = 0; rr < 4; ++rr)
    tile[lr + rr * 8][lc] = in[(size_t)(k0 + lr + rr * 8) * C + c0 + lc];
  __syncthreads();
#pragma unroll
  for (int rr = 0; rr < 4; ++rr)
    out[(size_t)(c0 + lr + rr * 8) * K + k0 + lc] = (__bf16)tile[lc][lr + rr * 8];
}

// ---------------------------------------------------------------------------
// qkv core: BM=256, BN=384, BK=32, 8 waves, LDS ring-of-4 (160KB).
// Phase t: vmcnt(10) [in flight t,t+1,t+2 -> retire tile t] ; barrier ;
// stage(t+3, (t+3)%4) [slot (t-1)%4, readers done before barrier t] ;
// read frags slot t%4 ; 48 MFMA. 2-phase issue lookahead.
struct SmemQ4 {
  __bf16 T[4][640][32];  // 160 KiB exactly (AITER attn uses 160KB on gfx950)
};

static __device__ __forceinline__ const bf16x8* fragq(const __bf16* base, int row, int g) {
  return (const bf16x8*)(base + row * 32 + (g ^ ((row >> 1) & 3)) * 8);
}

__global__ __launch_bounds__(512, 2) void gemm_qkv256b(const __bf16* __restrict__ A,
                                                       const __bf16* __restrict__ Bt,
                                                       __bf16* __restrict__ qb,
                                                       __bf16* __restrict__ kb,
                                                       __bf16* __restrict__ vtb) {
  __shared__ __align__(1024) SmemQ4 S;
  int sblk = blockIdx.x;
  int x = sblk & 7, i = sblk >> 3;
  int m0 = (i >> 1) * 256;
  int n0 = (2 * x + (i & 1)) * 384;
  const __bf16* Ab = A + (size_t)m0 * 2048;
  const __bf16* Bb = Bt + (size_t)n0 * 2048;

  int tid = threadIdx.x;
  int w = tid >> 6, lane = tid & 63;
  int ln15 = lane & 15, g = lane >> 4;
  int wr = w >> 2, wc = w & 3;
  int lr4 = lane >> 2, l3 = lane & 3;

  auto stage = [&](int kt, int rb) {
#pragma unroll
    for (int j = 0; j < 5; ++j) {
      int k = w + 8 * j;
      int row = k * 16 + lr4;
      int sg = l3 ^ ((row >> 1) & 3);
      const __bf16* src = (k < 16)
          ? Ab + (size_t)row * 2048 + kt * 32 + sg * 8
          : Bb + (size_t)(row - 256) * 2048 + kt * 32 + sg * 8;
      gload_lds16(src, &S.T[rb][k * 16][0]);
    }
  };

  f32x4 acc[8][6];
#pragma unroll
  for (int a = 0; a < 8; ++a)
#pragma unroll
    for (int nf = 0; nf < 6; ++nf) acc[a][nf] = (f32x4){0.f, 0.f, 0.f, 0.f};

  stage(0, 0);
  stage(1, 1);
  stage(2, 2);
  for (int t = 0; t < 64; ++t) {
    int rb = t & 3;
    asm volatile("s_waitcnt vmcnt(10)" ::: "memory");  // tile t landed
    __builtin_amdgcn_s_barrier();
    asm volatile("" ::: "memory");
    int ts = (t < 61) ? t + 3 : 63;  // tail re-stages tile 63 into dead slots
    stage(ts, (t + 3) & 3);
    const __bf16* Sb = &S.T[rb][0][0];
    bf16x8 bfr[6];
#pragma unroll
    for (int nf = 0; nf < 6; ++nf) {
      int row = 256 + wc * 96 + nf * 16 + ln15;
      bfr[nf] = *fragq(Sb, row, g);
    }
#pragma unroll
    for (int mh = 0; mh < 2; ++mh) {
      bf16x8 af[4];
#pragma unroll
      for (int a = 0; a < 4; ++a) {
        int row = wr * 128 + (mh * 4 + a) * 16 + ln15;
        af[a] = *fragq(Sb, row, g);
      }
      __builtin_amdgcn_s_setprio(1);
#pragma unroll
      for (int a = 0; a < 4; ++a)
#pragma unroll
        for (int nf = 0; nf < 6; ++nf)
          acc[mh * 4 + a][nf] = MFMA_BF16(af[a], bfr[nf], acc[mh * 4 + a][nf]);
      __builtin_amdgcn_s_setprio(0);
    }
  }
  asm volatile("s_waitcnt vmcnt(0)" ::: "memory");  // drain junk prefetch

#pragma unroll
  for (int nf = 0; nf < 6; ++nf) {
    int ng = n0 + wc * 96 + nf * 16 + ln15;
    int qkv = ng >> 11;
    int h = (ng >> 7) & 15;
    int d = ng & 127;
#pragma unroll
    for (int mf = 0; mf < 8; ++mf)
#pragma unroll
      for (int rr = 0; rr < 4; ++rr) {
        int m = m0 + wr * 128 + mf * 16 + g * 4 + rr;
        int b = m >> 11, n = m & 2047;
        int bh = b * NH + h;
        float v = acc[mf][nf][rr];
        if (qkv == 0)
          qb[((size_t)bh * NSEQ + n) * NDH + d] = (__bf16)(v * SCALE_Q);
        else if (qkv == 1)
          kb[((size_t)bh * NSEQ + n) * NDH + d] = (__bf16)v;
        else
          vtb[((size_t)bh * NDH + d) * NSEQ + n] = (__bf16)v;
      }
  }
}

// ---------------------------------------------------------------------------
// gemm_out: same ring template. BM=256, BN=128, BK=32, 8 waves (2Mx4N,
// wave=128x32), tile [384][32]=24KB, ring-of-6 (144KB), vmcnt(12),
// 4-phase lookahead. Grid 16x16 = 256 blocks, n-band XCD map (1MB B-band).
struct SmemO {
  __bf16 T[6][384][32];  // 144 KiB
};

__global__ __launch_bounds__(512, 2) void gemm_out256r(const __bf16* __restrict__ A,
                                                       const __bf16* __restrict__ Bt,
                                                       float* __restrict__ out) {
  __shared__ __align__(1024) SmemO S;
  int sblk = blockIdx.x;
  int x = sblk & 7, i = sblk >> 3;         // i: 0..31
  int m0 = (i >> 1) * 256;                 // 16 m-tiles
  int n0 = (2 * x + (i & 1)) * 128;        // XCD x owns n-tiles {2x,2x+1}
  const __bf16* Ab = A + (size_t)m0 * 2048;
  const __bf16* Bb = Bt + (size_t)n0 * 2048;

  int tid = threadIdx.x;
  int w = tid >> 6, lane = tid & 63;
  int ln15 = lane & 15, g = lane >> 4;
  int wr = w >> 2, wc = w & 3;
  int lr4 = lane >> 2, l3 = lane & 3;

  // 24 chunks of 1KB (16 rows); rows 0..255 = A, 256..383 = B. 3 chunks/wave.
  auto stage = [&](int kt, int rb) {
#pragma unroll
    for (int j = 0; j < 3; ++j) {
      int k = w + 8 * j;
      int row = k * 16 + lr4;
      int sg = l3 ^ ((row >> 1) & 3);
      const __bf16* src = (k < 16)
          ? Ab + (size_t)row * 2048 + kt * 32 + sg * 8
          : Bb + (size_t)(row - 256) * 2048 + kt * 32 + sg * 8;
      gload_lds16(src, &S.T[rb][k * 16][0]);
    }
  };

  f32x4 acc[8][2];
#pragma unroll
  for (int a = 0; a < 8; ++a)
#pragma unroll
    for (int nf = 0; nf < 2; ++nf) acc[a][nf] = (f32x4){0.f, 0.f, 0.f, 0.f};

  stage(0, 0);
  stage(1, 1);
  stage(2, 2);
  stage(3, 3);
  stage(4, 4);
  for (int t = 0; t < 64; ++t) {
    int rb = t % 6;
    asm volatile("s_waitcnt vmcnt(12)" ::: "memory");  // tile t landed
    __builtin_amdgcn_s_barrier();
    asm volatile("" ::: "memory");
    int ts = (t < 59) ? t + 5 : 63;
    stage(ts, (t + 5) % 6);
    const __bf16* Sb = &S.T[rb][0][0];
    bf16x8 bfr[2];
#pragma unroll
    for (int nf = 0; nf < 2; ++nf) {
      int row = 256 + wc * 32 + nf * 16 + ln15;
      bfr[nf] = *fragq(Sb, row, g);
    }
#pragma unroll
    for (int mh = 0; mh < 2; ++mh) {
      bf16x8 af[4];
#pragma unroll
      for (int a = 0; a < 4; ++a) {
        int row = wr * 128 + (mh * 4 + a) * 16 + ln15;
        af[a] = *fragq(Sb, row, g);
      }
      __builtin_amdgcn_s_setprio(1);
#pragma unroll
      for (int a = 0; a < 4; ++a)
#pragma unroll
        for (int nf = 0; nf < 2; ++nf)
          acc[mh * 4 + a][nf] = MFMA_BF16(af[a], bfr[nf], acc[mh * 4 + a][nf]);
      __builtin_amdgcn_s_setprio(0);
    }
  }
  asm volatile("s_waitcnt vmcnt(0)" ::: "memory");

#pragma unroll
  for (int mf = 0; mf < 8; ++mf)
#pragma unroll
    for (int nf = 0; nf < 2; ++nf)
#pragma unroll
      for (int rr = 0; rr < 4; ++rr) {
        int m = m0 + wr * 128 + mf * 16 + g * 4 + rr;
        int c = n0 + wc * 32 + nf * 16 + ln15;
        out[(size_t)m * NDIM + c] = acc[mf][nf][rr];
      }
}

// ---------------------------------------------------------------------------
// Flash attention (exact R11): 256 thr / 4 waves, dual-q (lo,31-lo), 512
// blocks = 2/CU, dbuf KV + counted vmcnt(8), fixed-max softmax, fused softcap.
static __device__ __forceinline__ void softcap_p(const f32x4* accS, float (*p)[4],
                                                 float& l_r, int j0, int q0s,
                                                 bool diag, int ln15, int g) {
#pragma unroll
  for (int jt = 0; jt < 4; ++jt)
#pragma unroll
    for (int r = 0; r < 4; ++r) {
      float e2 = __builtin_amdgcn_exp2f(accS[jt][r] * 0.057707801635558536f);
      float rc = __builtin_amdgcn_rcpf(e2 + 1.f);
      float pv = __builtin_amdgcn_exp2f(fmaf(rc, -144.26950408889634f, 54.82241155378061f));
      if (diag && (j0 + jt * 16 + g * 4 + r > q0s + ln15)) pv = 0.f;
      p[jt][r] = pv;
      l_r += pv;
    }
}

static __device__ __forceinline__ bf16x8 build_pa(const float (*p)[4], int c,
                                                  int lane_lo, int lane_hi, int g) {
  unsigned P0w0 = pack2_bf16(p[2 * c][0], p[2 * c][1]);
  unsigned P0w1 = pack2_bf16(p[2 * c][2], p[2 * c][3]);
  unsigned P1w0 = pack2_bf16(p[2 * c + 1][0], p[2 * c + 1][1]);
  unsigned P1w1 = pack2_bf16(p[2 * c + 1][2], p[2 * c + 1][3]);
  unsigned a0 = (unsigned)__shfl((int)P0w0, lane_lo);
  unsigned a1 = (unsigned)__shfl((int)P0w1, lane_lo);
  unsigned b0 = (unsigned)__shfl((int)P1w0, lane_lo);
  unsigned b1 = (unsigned)__shfl((int)P1w1, lane_lo);
  unsigned c0 = (unsigned)__shfl((int)P0w0, lane_hi);
  unsigned c1 = (unsigned)__shfl((int)P0w1, lane_hi);
  unsigned e0 = (unsigned)__shfl((int)P1w0, lane_hi);
  unsigned e1 = (unsigned)__shfl((int)P1w1, lane_hi);
  union { unsigned u[4]; bf16x8 v; } pu;
  pu.u[0] = (g < 2) ? a0 : b0;
  pu.u[1] = (g < 2) ? a1 : b1;
  pu.u[2] = (g < 2) ? c0 : e0;
  pu.u[3] = (g < 2) ? c1 : e1;
  return pu.v;
}

static __device__ __forceinline__ void attn_tile2(const __bf16* __restrict__ Kl,
                                                  const __bf16* __restrict__ Vl,
                                                  const bf16x8* qfh, const bf16x8* qfl,
                                                  f32x4* acc_h, f32x4* acc_l,
                                                  float& l_h, float& l_l,
                                                  int j0, int q0h, int q0l,
                                                  bool diag_h, bool diag_l, bool do_lo,
                                                  int ln15, int g) {
  f32x4 sh[4], sl[4];
#pragma unroll
  for (int jt = 0; jt < 4; ++jt) {
    sh[jt] = (f32x4){0.f, 0.f, 0.f, 0.f};
    sl[jt] = (f32x4){0.f, 0.f, 0.f, 0.f};
  }
  __builtin_amdgcn_s_setprio(1);
#pragma unroll
  for (int jt = 0; jt < 4; ++jt)
#pragma unroll
    for (int kc = 0; kc < 4; ++kc) {
      int row = jt * 16 + ln15;
      int bc = (kc * 64 + g * 16) ^ ((row & 7) << 4);
      bf16x8 kf = *reinterpret_cast<const bf16x8*>(Kl + row * 128 + (bc >> 1));
      sh[jt] = MFMA_BF16(kf, qfh[kc], sh[jt]);
      if (do_lo) sl[jt] = MFMA_BF16(kf, qfl[kc], sl[jt]);
    }
  __builtin_amdgcn_s_setprio(0);
  float ph[4][4], pl[4][4];
  softcap_p(sh, ph, l_h, j0, q0h, diag_h, ln15, g);
  if (do_lo) softcap_p(sl, pl, l_l, j0, q0l, diag_l, ln15, g);
  int lane_lo = ln15 + 32 * (g & 1);
  int lane_hi = lane_lo + 16;
#pragma unroll
  for (int c = 0; c < 2; ++c) {
    bf16x8 pah = build_pa(ph, c, lane_lo, lane_hi, g);
    bf16x8 pal = build_pa(pl, c, lane_lo, lane_hi, g);
    __builtin_amdgcn_s_setprio(1);
#pragma unroll
    for (int d0 = 0; d0 < 8; ++d0) {
      int d = d0 * 16 + ln15;
      int bc = (c * 64 + g * 16) ^ ((d & 7) << 4);
      bf16x8 vf = *reinterpret_cast<const bf16x8*>(Vl + d * 64 + (bc >> 1));
      acc_h[d0] = MFMA_BF16(pah, vf, acc_h[d0]);
      if (do_lo) acc_l[d0] = MFMA_BF16(pal, vf, acc_l[d0]);
    }
    __builtin_amdgcn_s_setprio(0);
  }
}

__global__ __launch_bounds__(256, 2) void attn_kernel(const __bf16* __restrict__ qb,
                                                      const __bf16* __restrict__ kb,
                                                      const __bf16* __restrict__ vtb,
                                                      const float* __restrict__ gates,
                                                      __bf16* __restrict__ og) {
  __shared__ __align__(1024) __bf16 Kl[2][64 * 128];
  __shared__ __align__(1024) __bf16 Vl[2][128 * 64];
  int tid = threadIdx.x;
  int w = tid >> 6, lane = tid & 63;
  int ln15 = lane & 15, g = lane >> 4;
  int bx = blockIdx.x;
  int lo = bx & 15, bh = bx >> 4;
  int hi = 31 - lo;
  const __bf16* qh = qb + (size_t)bh * NSEQ * NDH;
  const __bf16* kh = kb + (size_t)bh * NSEQ * NDH;
  const __bf16* vh = vtb + (size_t)bh * NDH * NSEQ;

  int q0h = hi * 64 + w * 16;
  int q0l = lo * 64 + w * 16;
  bf16x8 qfh[4], qfl[4];
#pragma unroll
  for (int kc = 0; kc < 4; ++kc) {
    qfh[kc] = *reinterpret_cast<const bf16x8*>(qh + (size_t)(q0h + ln15) * NDH + kc * 32 + g * 8);
    qfl[kc] = *reinterpret_cast<const bf16x8*>(qh + (size_t)(q0l + ln15) * NDH + kc * 32 + g * 8);
  }

  f32x4 acc_h[8], acc_l[8];
#pragma unroll
  for (int d0 = 0; d0 < 8; ++d0) {
    acc_h[d0] = (f32x4){0.f, 0.f, 0.f, 0.f};
    acc_l[d0] = (f32x4){0.f, 0.f, 0.f, 0.f};
  }
  float l_h = 0.f, l_l = 0.f;

  auto stage = [&](int t, int buf) {
    int j0 = t * 64;
#pragma unroll
    for (int i = 0; i < 4; ++i) {
      int gi = (i * 4 + w) * 64 + lane;
      int kr = gi >> 4, kcs = gi & 15;
      int kc_ = kcs ^ (kr & 7);
      gload_lds16(kh + (size_t)(j0 + kr) * NDH + kc_ * 8, &Kl[buf][(i * 4 + w) * 512]);
      int vr = gi >> 3, vcs = gi & 7;
      int vc_ = vcs ^ (vr & 7);
      gload_lds16(vh + (size_t)vr * NSEQ + j0 + vc_ * 8, &Vl[buf][(i * 4 + w) * 512]);
    }
  };

  stage(0, 0);
  for (int t = 0; t <= hi; ++t) {
    int cb = t & 1;
    if (t < hi) {
      stage(t + 1, cb ^ 1);
      asm volatile("s_waitcnt vmcnt(8)" ::: "memory");
    } else {
      asm volatile("s_waitcnt vmcnt(0)" ::: "memory");
    }
    __builtin_amdgcn_s_barrier();
    attn_tile2(&Kl[cb][0], &Vl[cb][0], qfh, qfl, acc_h, acc_l, l_h, l_l,
               t * 64, q0h, q0l, t == hi, t == lo, t <= lo, ln15, g);
    __builtin_amdgcn_s_barrier();
  }

  l_h += __shfl_xor(l_h, 16); l_h += __shfl_xor(l_h, 32);
  l_l += __shfl_xor(l_l, 16); l_l += __shfl_xor(l_l, 32);

  int b = bh >> 4, h = bh & 15;
#pragma unroll
  for (int set = 0; set < 2; ++set) {
    int q0s = set ? q0l : q0h;
    f32x4* acc = set ? acc_l : acc_h;
    float lr = set ? l_l : l_h;
    float gv[4];
#pragma unroll
    for (int r = 0; r < 4; ++r) {
      float lv = __shfl(lr, g * 4 + r);
      int row = q0s + g * 4 + r;
      gv[r] = gates[(size_t)bh * NSEQ + row] / lv;
    }
#pragma unroll
    for (int d0 = 0; d0 < 8; ++d0)
#pragma unroll
      for (int r = 0; r < 4; ++r) {
        int row = q0s + g * 4 + r;
        og[((size_t)(b * NSEQ + row)) * NDIM + h * NDH + d0 * 16 + ln15] =
            (__bf16)(acc[d0][r] * gv[r]);
      }
  }
}

// ---------------------------------------------------------------------------
extern "C" void kernel_launch(void* const* d_in, const int* in_sizes, int n_in,
                              void* d_out, int out_size, void* d_ws, size_t ws_size,
                              hipStream_t stream) {
  const float* x = (const float*)d_in[0];
  const float* w_qkv = (const float*)d_in[1];
  const float* w_gates = (const float*)d_in[2];
  const float* w_out = (const float*)d_in[3];
  float* out = (float*)d_out;
  char* ws = (char*)d_ws;

  __bf16* x_bf   = (__bf16*)(ws + 0);          // 16,777,216
  __bf16* wqkv_t = (__bf16*)(ws + 16777216);   // 25,165,824
  __bf16* wout_t = (__bf16*)(ws + 41943040);   // 8,388,608
  __bf16* q_buf  = (__bf16*)(ws + 50331648);   // 16,777,216
  __bf16* k_buf  = (__bf16*)(ws + 67108864);   // 16,777,216
  __bf16* vt_buf = (__bf16*)(ws + 83886080);   // 16,777,216
  float*  gates  = (float*)(ws + 100663296);   // 262,144
  __bf16* attn_g = (__bf16*)(ws + 100925440);  // 16,777,216

  cvt_gates_kernel<<<4096, 256, 0, stream>>>(x, w_gates, x_bf, gates);
  transpose_cvt_kernel<<<dim3(192, 64), 256, 0, stream>>>(w_qkv, wqkv_t, 2048, 6144);
  transpose_cvt_kernel<<<dim3(64, 64), 256, 0, stream>>>(w_out, wout_t, 2048, 2048);
  gemm_qkv256b<<<256, 512, 0, stream>>>(x_bf, wqkv_t, q_buf, k_buf, vt_buf);
  attn_kernel<<<512, 256, 0, stream>>>(q_buf, k_buf, vt_buf, gates, attn_g);
  gemm_out256r<<<256, 512, 0, stream>>>(attn_g, wout_t, out);
}